// Round 1
// baseline (5698.346 us; speedup 1.0000x reference)
//
#include <hip/hip_runtime.h>
#include <math.h>

// ---------------- helpers ----------------
__device__ __forceinline__ float fast_sigmoid(float x) { return 1.0f / (1.0f + __expf(-x)); }
__device__ __forceinline__ float fast_tanh(float x) {
    float a = fabsf(x);
    float e = __expf(-2.0f * a);
    float t = (1.0f - e) / (1.0f + e);
    return copysignf(t, x);
}

// ---------------- prep kernels ----------------
__global__ void bias_kernel(const float* __restrict__ bih, const float* __restrict__ bhh,
                            float* __restrict__ ball, int n) {
    int t = blockIdx.x * blockDim.x + threadIdx.x;
    if (t < n) ball[t] = bih[t] + bhh[t];
}

// WT[k][j] = (k < Kih) ? Wih[j][kOff + k] : Whh[j][k - Kih]; j in [0,512)
__global__ void wt_kernel(const float* __restrict__ Wih, int ldih,
                          const float* __restrict__ Whh,
                          int Kih, int Ktot, float* __restrict__ WT) {
    int t = blockIdx.x * blockDim.x + threadIdx.x;
    if (t >= Ktot * 512) return;
    int k = t >> 9;
    int j = t & 511;
    float v = (k < Kih) ? Wih[j * ldih + k] : Whh[j * 128 + (k - Kih)];
    WT[t] = v;
}

__global__ void feat0_kernel(const float* __restrict__ features, const float* __restrict__ W_in,
                             const float* __restrict__ b_in, float* __restrict__ feat, int n) {
    int t = blockIdx.x * blockDim.x + threadIdx.x;
    if (t >= n * 128) return;
    int node = t >> 7;
    int d = t & 127;
    float s = b_in[d];
#pragma unroll
    for (int k = 0; k < 6; ++k) s += features[node * 6 + k] * W_in[k * 128 + d];
    feat[t] = fmaxf(s, 0.0f);
}

__global__ void hist_kernel(const int* __restrict__ dst, int* __restrict__ cnt, int e) {
    int t = blockIdx.x * blockDim.x + threadIdx.x;
    if (t < e) atomicAdd(&cnt[dst[t]], 1);
}

__global__ void scan_kernel(const int* __restrict__ cnt, int* __restrict__ off,
                            int* __restrict__ cur, float* __restrict__ recip, int n) {
    __shared__ int sums[1024];
    int t = threadIdx.x;
    int chunk = (n + 1023) >> 10;
    int s0 = t * chunk;
    int s1 = s0 + chunk; if (s1 > n) s1 = n;
    int s = 0;
    for (int i = s0; i < s1; ++i) s += cnt[i];
    sums[t] = s;
    __syncthreads();
    if (t == 0) {
        int acc = 0;
        for (int i = 0; i < 1024; ++i) { int v = sums[i]; sums[i] = acc; acc += v; }
        off[n] = acc;
    }
    __syncthreads();
    int acc = sums[t];
    for (int i = s0; i < s1; ++i) {
        off[i] = acc; cur[i] = acc;
        int c = cnt[i];
        recip[i] = (c > 0) ? 1.0f / (float)c : 0.0f;
        acc += c;
    }
}

__global__ void scatter_kernel(const int* __restrict__ src, const int* __restrict__ dst,
                               int* __restrict__ cur, int* __restrict__ esrc, int e) {
    int t = blockIdx.x * blockDim.x + threadIdx.x;
    if (t >= e) return;
    int d = dst[t];
    int p = atomicAdd(&cur[d], 1);
    esrc[p] = src[t];
}

// pull-based mean aggregation: one block (128 threads) per node, thread = feature dim
__global__ void agg_kernel(const float* __restrict__ feat, const int* __restrict__ off,
                           const int* __restrict__ esrc, const float* __restrict__ recip,
                           float* __restrict__ agg) {
    int v = blockIdx.x;
    int t = threadIdx.x;  // 0..127
    int e0 = off[v], e1 = off[v + 1];
    float a = 0.0f;
    for (int e = e0; e < e1; ++e) {
        int s = esrc[e];
        a += feat[s * 128 + t];
    }
    agg[v * 128 + t] = a * recip[v];
}

// ---------------- fused GEMM + LSTM cell ----------------
// gates[n, 0:512] = sum_p A_p[n,:] @ WT_p + b ; then i,f,g,o -> h_new, c_new
// BM=64 rows, BN=512 (all gates), BK=32, 512 threads.
// thread (cg = tid&31, rg = tid>>5) owns rows row0+4*rg..+3, dims 4*cg..+3, all 4 gates.
#define BM 64
#define BK 32
#define LDA 68    // As row stride (floats), padded
#define LDB 516   // Bs row stride (floats), padded

template <int PARTS>
__global__ __launch_bounds__(512, 4) void gemm_lstm(
    const float* __restrict__ A0, const float* __restrict__ A1, const float* __restrict__ A2,
    const float* __restrict__ WT, const float* __restrict__ bvec,
    const float* __restrict__ c_in, float* __restrict__ c_out, float* __restrict__ h_out,
    int nrows) {
    __shared__ float As[BK * LDA];  // [k][r]
    __shared__ float Bs[BK * LDB];  // [k][c]

    const int tid = threadIdx.x;
    const int row0 = blockIdx.x * BM;
    const int cg = tid & 31;   // col group 0..31 -> dims 4*cg..4*cg+3
    const int rg = tid >> 5;   // row group 0..15 -> rows 4*rg..4*rg+3

    float acc[4][4][4];  // [row i][gate q][dim j]
#pragma unroll
    for (int q = 0; q < 4; ++q) {
        float4 b4 = *(const float4*)&bvec[(q << 7) + (cg << 2)];
#pragma unroll
        for (int i = 0; i < 4; ++i) {
            acc[i][q][0] = b4.x; acc[i][q][1] = b4.y; acc[i][q][2] = b4.z; acc[i][q][3] = b4.w;
        }
    }

    const int KT = PARTS * 4;   // number of BK tiles (128/BK per part)
    const int a_r = tid >> 3;          // 0..63
    const int a_kc = (tid & 7) << 2;   // 0,4,...,28

    for (int kt = 0; kt < KT; ++kt) {
        // select A part (each BK tile lies fully inside one 128-wide part)
        const float* Ap = A0;
        int pi = kt >> 2;
        if (PARTS >= 2 && pi == 1) Ap = A1;
        if (PARTS >= 3 && pi == 2) Ap = A2;
        int kk = (kt & 3) * BK;

        // global loads (issue all before barrier)
        int n = row0 + a_r;
        float4 av = make_float4(0.f, 0.f, 0.f, 0.f);
        if (n < nrows) av = *(const float4*)&Ap[n * 128 + kk + a_kc];
        float4 bv[8];
#pragma unroll
        for (int i = 0; i < 8; ++i) {
            int t2 = i * 512 + tid;
            int k = t2 >> 7;           // 0..31
            int j4 = (t2 & 127) << 2;  // col
            bv[i] = *(const float4*)&WT[(kt * BK + k) * 512 + j4];
        }

        __syncthreads();  // previous tile's compute done reading LDS
        As[(a_kc + 0) * LDA + a_r] = av.x;
        As[(a_kc + 1) * LDA + a_r] = av.y;
        As[(a_kc + 2) * LDA + a_r] = av.z;
        As[(a_kc + 3) * LDA + a_r] = av.w;
#pragma unroll
        for (int i = 0; i < 8; ++i) {
            int t2 = i * 512 + tid;
            int k = t2 >> 7;
            int j4 = (t2 & 127) << 2;
            *(float4*)&Bs[k * LDB + j4] = bv[i];
        }
        __syncthreads();

#pragma unroll 8
        for (int k = 0; k < BK; ++k) {
            const float4 a4 = *(const float4*)&As[k * LDA + (rg << 2)];
            float4 bq[4];
#pragma unroll
            for (int q = 0; q < 4; ++q) bq[q] = *(const float4*)&Bs[k * LDB + (q << 7) + (cg << 2)];
#pragma unroll
            for (int i = 0; i < 4; ++i) {
                float a_i = (i == 0) ? a4.x : (i == 1) ? a4.y : (i == 2) ? a4.z : a4.w;
#pragma unroll
                for (int q = 0; q < 4; ++q) {
                    acc[i][q][0] += a_i * bq[q].x;
                    acc[i][q][1] += a_i * bq[q].y;
                    acc[i][q][2] += a_i * bq[q].z;
                    acc[i][q][3] += a_i * bq[q].w;
                }
            }
        }
    }

    // epilogue: LSTM gates, fully in-register
    const int d0 = cg << 2;
#pragma unroll
    for (int i = 0; i < 4; ++i) {
        int n = row0 + (rg << 2) + i;
        if (n < nrows) {
            float4 cold = *(const float4*)&c_in[n * 128 + d0];
            float4 cnew, hnew;
#pragma unroll
            for (int j = 0; j < 4; ++j) {
                float ig = fast_sigmoid(acc[i][0][j]);
                float fg = fast_sigmoid(acc[i][1][j]);
                float gg = fast_tanh(acc[i][2][j]);
                float og = fast_sigmoid(acc[i][3][j]);
                float cc = (j == 0) ? cold.x : (j == 1) ? cold.y : (j == 2) ? cold.z : cold.w;
                float cn = fg * cc + ig * gg;
                float hn = og * fast_tanh(cn);
                ((float*)&cnew)[j] = cn;
                ((float*)&hnew)[j] = hn;
            }
            *(float4*)&c_out[n * 128 + d0] = cnew;
            *(float4*)&h_out[n * 128 + d0] = hnew;
        }
    }
}

// ---------------- output projection ----------------
__global__ void out_kernel(const float* __restrict__ h2, const float* __restrict__ Wout,
                           const float* __restrict__ bout, float* __restrict__ out) {
    int n = blockIdx.x;
    int l = threadIdx.x;  // 0..63
    float v = h2[n * 128 + l] * Wout[l] + h2[n * 128 + 64 + l] * Wout[64 + l];
#pragma unroll
    for (int o = 32; o > 0; o >>= 1) v += __shfl_down(v, o, 64);
    if (l == 0) out[n] = v + bout[0];
}

// ---------------- launch ----------------
extern "C" void kernel_launch(void* const* d_in, const int* in_sizes, int n_in,
                              void* d_out, int out_size, void* d_ws, size_t ws_size,
                              hipStream_t stream) {
    const float* features = (const float*)d_in[0];
    const int*   src      = (const int*)d_in[1];
    const int*   dst      = (const int*)d_in[2];
    const float* W_in     = (const float*)d_in[3];
    const float* b_in     = (const float*)d_in[4];
    const float* Wih0     = (const float*)d_in[5];
    const float* Wih_rest = (const float*)d_in[6];
    const float* Whh      = (const float*)d_in[7];
    const float* bih      = (const float*)d_in[8];
    const float* bhh      = (const float*)d_in[9];
    const float* W_out    = (const float*)d_in[10];
    const float* b_out    = (const float*)d_in[11];
    float* out = (float*)d_out;

    const int N = in_sizes[0] / 6;  // 20000
    const int E = in_sizes[1];      // 640000

    // workspace carve-up
    char* ws = (char*)d_ws;
    size_t pos = 0;
    auto alloc = [&](size_t bytes) -> void* {
        void* p = ws + pos;
        pos = (pos + bytes + 255) & ~(size_t)255;
        return p;
    };
    const size_t fbytes = (size_t)N * 128 * sizeof(float);
    float* feat0  = (float*)alloc(fbytes);
    float* aggb   = (float*)alloc(fbytes);
    float* hcbase = (float*)alloc(6 * fbytes);
    float* h0 = hcbase + 0 * (size_t)N * 128;
    float* c0 = hcbase + 1 * (size_t)N * 128;
    float* h1 = hcbase + 2 * (size_t)N * 128;
    float* c1 = hcbase + 3 * (size_t)N * 128;
    float* h2 = hcbase + 4 * (size_t)N * 128;
    float* c2 = hcbase + 5 * (size_t)N * 128;
    float* WT0  = (float*)alloc((size_t)384 * 512 * 4);
    float* WT1  = (float*)alloc((size_t)256 * 512 * 4);
    float* WT2  = (float*)alloc((size_t)256 * 512 * 4);
    float* ball = (float*)alloc((size_t)3 * 512 * 4);
    int*   cnt   = (int*)alloc((size_t)N * 4);
    int*   offs  = (int*)alloc((size_t)(N + 1) * 4);
    int*   cur   = (int*)alloc((size_t)N * 4);
    int*   esrc  = (int*)alloc((size_t)E * 4);
    float* recip = (float*)alloc((size_t)N * 4);

    // zero-init state + histogram
    hipMemsetAsync(hcbase, 0, 6 * fbytes, stream);
    hipMemsetAsync(cnt, 0, (size_t)N * 4, stream);

    bias_kernel<<<(3 * 512 + 255) / 256, 256, 0, stream>>>(bih, bhh, ball, 3 * 512);
    wt_kernel<<<(384 * 512 + 255) / 256, 256, 0, stream>>>(Wih0, 256, Whh, 256, 384, WT0);
    wt_kernel<<<(256 * 512 + 255) / 256, 256, 0, stream>>>(Wih_rest, 128, Whh + 512 * 128, 128, 256, WT1);
    wt_kernel<<<(256 * 512 + 255) / 256, 256, 0, stream>>>(Wih_rest + 512 * 128, 128, Whh + 2 * 512 * 128, 128, 256, WT2);
    feat0_kernel<<<(N * 128 + 255) / 256, 256, 0, stream>>>(features, W_in, b_in, feat0, N);
    hist_kernel<<<(E + 255) / 256, 256, 0, stream>>>(dst, cnt, E);
    scan_kernel<<<1, 1024, 0, stream>>>(cnt, offs, cur, recip, N);
    scatter_kernel<<<(E + 255) / 256, 256, 0, stream>>>(src, dst, cur, esrc, E);

    const int gx = (N + BM - 1) / BM;
    const float* featcur = feat0;
    for (int step = 0; step < 11; ++step) {
        agg_kernel<<<N, 128, 0, stream>>>(featcur, offs, esrc, recip, aggb);
        gemm_lstm<3><<<gx, 512, 0, stream>>>(aggb, featcur, h0, WT0, ball, c0, c0, h0, N);
        gemm_lstm<2><<<gx, 512, 0, stream>>>(h0, h1, nullptr, WT1, ball + 512, c1, c1, h1, N);
        gemm_lstm<2><<<gx, 512, 0, stream>>>(h1, h2, nullptr, WT2, ball + 1024, c2, c2, h2, N);
        featcur = h2;
    }
    out_kernel<<<N, 64, 0, stream>>>(h2, W_out, b_out, out);
}

// Round 2
// 4563.726 us; speedup vs baseline: 1.2486x; 1.2486x over previous
//
#include <hip/hip_runtime.h>
#include <math.h>

// ---------------- helpers ----------------
__device__ __forceinline__ float fast_sigmoid(float x) { return 1.0f / (1.0f + __expf(-x)); }
__device__ __forceinline__ float fast_tanh(float x) {
    float a = fabsf(x);
    float e = __expf(-2.0f * a);
    float t = (1.0f - e) / (1.0f + e);
    return copysignf(t, x);
}

// async global->LDS, 16B per lane. LDS dest = wave-uniform base + lane*16.
__device__ __forceinline__ void async_copy16(const float* gsrc, float* ldst) {
    __builtin_amdgcn_global_load_lds(
        (const __attribute__((address_space(1))) void*)gsrc,
        (__attribute__((address_space(3))) void*)ldst,
        16, 0, 0);
}

// ---------------- prep kernels ----------------
__global__ void bias_kernel(const float* __restrict__ bih, const float* __restrict__ bhh,
                            float* __restrict__ ball, int n) {
    int t = blockIdx.x * blockDim.x + threadIdx.x;
    if (t < n) ball[t] = bih[t] + bhh[t];
}

// WT[k][j] = (k < Kih) ? Wih[j][k] : Whh[j][k - Kih]; j in [0,512)
__global__ void wt_kernel(const float* __restrict__ Wih, int ldih,
                          const float* __restrict__ Whh,
                          int Kih, int Ktot, float* __restrict__ WT) {
    int t = blockIdx.x * blockDim.x + threadIdx.x;
    if (t >= Ktot * 512) return;
    int k = t >> 9;
    int j = t & 511;
    float v = (k < Kih) ? Wih[j * ldih + k] : Whh[j * 128 + (k - Kih)];
    WT[t] = v;
}

__global__ void feat0_kernel(const float* __restrict__ features, const float* __restrict__ W_in,
                             const float* __restrict__ b_in, float* __restrict__ feat, int n) {
    int t = blockIdx.x * blockDim.x + threadIdx.x;
    if (t >= n * 128) return;
    int node = t >> 7;
    int d = t & 127;
    float s = b_in[d];
#pragma unroll
    for (int k = 0; k < 6; ++k) s += features[node * 6 + k] * W_in[k * 128 + d];
    feat[t] = fmaxf(s, 0.0f);
}

__global__ void hist_kernel(const int* __restrict__ dst, int* __restrict__ cnt, int e) {
    int t = blockIdx.x * blockDim.x + threadIdx.x;
    if (t < e) atomicAdd(&cnt[dst[t]], 1);
}

__global__ void scan_kernel(const int* __restrict__ cnt, int* __restrict__ off,
                            int* __restrict__ cur, float* __restrict__ recip, int n) {
    __shared__ int sums[1024];
    int t = threadIdx.x;
    int chunk = (n + 1023) >> 10;
    int s0 = t * chunk;
    int s1 = s0 + chunk; if (s1 > n) s1 = n;
    int s = 0;
    for (int i = s0; i < s1; ++i) s += cnt[i];
    sums[t] = s;
    __syncthreads();
    if (t == 0) {
        int acc = 0;
        for (int i = 0; i < 1024; ++i) { int v = sums[i]; sums[i] = acc; acc += v; }
        off[n] = acc;
    }
    __syncthreads();
    int acc = sums[t];
    for (int i = s0; i < s1; ++i) {
        off[i] = acc; cur[i] = acc;
        int c = cnt[i];
        recip[i] = (c > 0) ? 1.0f / (float)c : 0.0f;
        acc += c;
    }
}

__global__ void scatter_kernel(const int* __restrict__ src, const int* __restrict__ dst,
                               int* __restrict__ cur, int* __restrict__ esrc, int e) {
    int t = blockIdx.x * blockDim.x + threadIdx.x;
    if (t >= e) return;
    int d = dst[t];
    int p = atomicAdd(&cur[d], 1);
    esrc[p] = src[t];
}

// pull-based mean aggregation: 32 lanes (float4 over 128 dims) per node,
// 8 nodes per 256-thread block, edge loop unrolled x4 for MLP.
__global__ void agg_kernel(const float* __restrict__ feat, const int* __restrict__ off,
                           const int* __restrict__ esrc, const float* __restrict__ recip,
                           float* __restrict__ agg, int n) {
    int slot = threadIdx.x >> 5;   // 0..7
    int lane = threadIdx.x & 31;   // dim group: lane*4
    int v = blockIdx.x * 8 + slot;
    if (v >= n) return;
    int e0 = off[v], e1 = off[v + 1];
    float4 a = make_float4(0.f, 0.f, 0.f, 0.f);
    int e = e0;
    for (; e + 4 <= e1; e += 4) {
        int s0 = esrc[e], s1 = esrc[e + 1], s2 = esrc[e + 2], s3 = esrc[e + 3];
        float4 v0 = *(const float4*)&feat[(size_t)s0 * 128 + lane * 4];
        float4 v1 = *(const float4*)&feat[(size_t)s1 * 128 + lane * 4];
        float4 v2 = *(const float4*)&feat[(size_t)s2 * 128 + lane * 4];
        float4 v3 = *(const float4*)&feat[(size_t)s3 * 128 + lane * 4];
        a.x += v0.x + v1.x + v2.x + v3.x;
        a.y += v0.y + v1.y + v2.y + v3.y;
        a.z += v0.z + v1.z + v2.z + v3.z;
        a.w += v0.w + v1.w + v2.w + v3.w;
    }
    for (; e < e1; ++e) {
        int s = esrc[e];
        float4 v0 = *(const float4*)&feat[(size_t)s * 128 + lane * 4];
        a.x += v0.x; a.y += v0.y; a.z += v0.z; a.w += v0.w;
    }
    float r = recip[v];
    *(float4*)&agg[(size_t)v * 128 + lane * 4] = make_float4(a.x * r, a.y * r, a.z * r, a.w * r);
}

// ---------------- fused GEMM + LSTM cell ----------------
// gates[n, 0:512] = sum_p A_p[n,:] @ WT_p + b ; then i,f,g,o -> h_new, c_new
// BM=64 rows, BN=512 (all gates), BK=32, 512 threads, global_load_lds staging.
// thread (cg = tid&31, rg = tid>>5) owns rows row0+4*rg..+3, dims 4*cg..+3, all 4 gates.
#define BM 64
#define BK 32

template <int PARTS>
__global__ __launch_bounds__(512, 4) void gemm_lstm(
    const float* __restrict__ A0, const float* __restrict__ A1, const float* __restrict__ A2,
    const float* __restrict__ WT, const float* __restrict__ bvec,
    const float* __restrict__ c_in, float* __restrict__ c_out, float* __restrict__ h_out,
    int nrows) {
    __shared__ float Bs[BK * 512];   // [k][j], 64 KB, unpadded (stride 512)
    __shared__ float As[BM * BK];    // [r][k], 8 KB, unpadded (stride 32)

    const int tid = threadIdx.x;
    const int wave = tid >> 6;   // 0..7
    const int lane = tid & 63;
    const int cg = tid & 31;     // dims 4*cg..4*cg+3
    const int rg = tid >> 5;     // rows 4*rg..4*rg+3

    float acc[4][4][4];  // [row i][gate q][dim j]
#pragma unroll
    for (int q = 0; q < 4; ++q) {
        float4 b4 = *(const float4*)&bvec[(q << 7) + (cg << 2)];
#pragma unroll
        for (int i = 0; i < 4; ++i) {
            acc[i][q][0] = b4.x; acc[i][q][1] = b4.y; acc[i][q][2] = b4.z; acc[i][q][3] = b4.w;
        }
    }

    const int row0 = blockIdx.x * BM;
    // A staging geometry: wave w stages rows w*8..w*8+7, lane l -> row w*8+(l>>3), col (l&7)*4
    const int a_r = (wave << 3) + (lane >> 3);
    const int a_c4 = (lane & 7) << 2;

    for (int kt = 0; kt < PARTS * 4; ++kt) {
        const float* Ap = A0;
        int pi = kt >> 2;
        if (PARTS >= 2 && pi == 1) Ap = A1;
        if (PARTS >= 3 && pi == 2) Ap = A2;
        const int kk = (kt & 3) * BK;

        __syncthreads();  // previous tile's compute done reading LDS
        // stage A (8 KB): 1 call per wave. NOTE: A buffers are padded to N+64 rows.
        async_copy16(&Ap[(size_t)(row0 + a_r) * 128 + kk + a_c4], &As[wave << 8]);
        // stage B (64 KB): 8 calls per wave, chunk = i*8 + wave covers 256 floats.
        {
            const float* bbase = &WT[(size_t)kt * BK * 512];
#pragma unroll
            for (int i = 0; i < 8; ++i) {
                int c = (i << 3) + wave;
                async_copy16(&bbase[(c << 8) + (lane << 2)], &Bs[c << 8]);
            }
        }
        __syncthreads();  // drains vmcnt(0): staging complete

        for (int k4 = 0; k4 < BK; k4 += 4) {
            float4 a[4];
#pragma unroll
            for (int i = 0; i < 4; ++i)
                a[i] = *(const float4*)&As[((rg << 2) + i) * BK + k4];
#pragma unroll
            for (int kk2 = 0; kk2 < 4; ++kk2) {
                float4 bq[4];
#pragma unroll
                for (int q = 0; q < 4; ++q)
                    bq[q] = *(const float4*)&Bs[(k4 + kk2) * 512 + (q << 7) + (cg << 2)];
#pragma unroll
                for (int i = 0; i < 4; ++i) {
                    float ai = (kk2 == 0) ? a[i].x : (kk2 == 1) ? a[i].y : (kk2 == 2) ? a[i].z : a[i].w;
#pragma unroll
                    for (int q = 0; q < 4; ++q) {
                        acc[i][q][0] += ai * bq[q].x;
                        acc[i][q][1] += ai * bq[q].y;
                        acc[i][q][2] += ai * bq[q].z;
                        acc[i][q][3] += ai * bq[q].w;
                    }
                }
            }
        }
    }

    // epilogue: LSTM gates, fully in-register
    const int d0 = cg << 2;
#pragma unroll
    for (int i = 0; i < 4; ++i) {
        int n = row0 + (rg << 2) + i;
        if (n < nrows) {
            float4 cold = *(const float4*)&c_in[(size_t)n * 128 + d0];
            float4 cnew, hnew;
#pragma unroll
            for (int j = 0; j < 4; ++j) {
                float ig = fast_sigmoid(acc[i][0][j]);
                float fg = fast_sigmoid(acc[i][1][j]);
                float gg = fast_tanh(acc[i][2][j]);
                float og = fast_sigmoid(acc[i][3][j]);
                float cc = (j == 0) ? cold.x : (j == 1) ? cold.y : (j == 2) ? cold.z : cold.w;
                float cn = fg * cc + ig * gg;
                float hn = og * fast_tanh(cn);
                ((float*)&cnew)[j] = cn;
                ((float*)&hnew)[j] = hn;
            }
            *(float4*)&c_out[(size_t)n * 128 + d0] = cnew;
            *(float4*)&h_out[(size_t)n * 128 + d0] = hnew;
        }
    }
}

// ---------------- output projection ----------------
__global__ void out_kernel(const float* __restrict__ h2, const float* __restrict__ Wout,
                           const float* __restrict__ bout, float* __restrict__ out) {
    int n = blockIdx.x;
    int l = threadIdx.x;  // 0..63
    float v = h2[(size_t)n * 128 + l] * Wout[l] + h2[(size_t)n * 128 + 64 + l] * Wout[64 + l];
#pragma unroll
    for (int o = 32; o > 0; o >>= 1) v += __shfl_down(v, o, 64);
    if (l == 0) out[n] = v + bout[0];
}

// ---------------- launch ----------------
extern "C" void kernel_launch(void* const* d_in, const int* in_sizes, int n_in,
                              void* d_out, int out_size, void* d_ws, size_t ws_size,
                              hipStream_t stream) {
    const float* features = (const float*)d_in[0];
    const int*   src      = (const int*)d_in[1];
    const int*   dst      = (const int*)d_in[2];
    const float* W_in     = (const float*)d_in[3];
    const float* b_in     = (const float*)d_in[4];
    const float* Wih0     = (const float*)d_in[5];
    const float* Wih_rest = (const float*)d_in[6];
    const float* Whh      = (const float*)d_in[7];
    const float* bih      = (const float*)d_in[8];
    const float* bhh      = (const float*)d_in[9];
    const float* W_out    = (const float*)d_in[10];
    const float* b_out    = (const float*)d_in[11];
    float* out = (float*)d_out;

    const int N = in_sizes[0] / 6;  // 20000
    const int E = in_sizes[1];      // 640000
    const int NP = N + BM;          // padded rows so A-staging never reads OOB

    // workspace carve-up
    char* ws = (char*)d_ws;
    size_t pos = 0;
    auto alloc = [&](size_t bytes) -> void* {
        void* p = ws + pos;
        pos = (pos + bytes + 255) & ~(size_t)255;
        return p;
    };
    const size_t frow = 128;
    const size_t fbytes = (size_t)NP * frow * sizeof(float);
    float* feat0  = (float*)alloc(fbytes);
    float* aggb   = (float*)alloc(fbytes);
    float* hcbase = (float*)alloc(6 * fbytes);
    float* h0 = hcbase + 0 * (size_t)NP * frow;
    float* c0 = hcbase + 1 * (size_t)NP * frow;
    float* h1 = hcbase + 2 * (size_t)NP * frow;
    float* c1 = hcbase + 3 * (size_t)NP * frow;
    float* h2 = hcbase + 4 * (size_t)NP * frow;
    float* c2 = hcbase + 5 * (size_t)NP * frow;
    float* WT0  = (float*)alloc((size_t)384 * 512 * 4);
    float* WT1  = (float*)alloc((size_t)256 * 512 * 4);
    float* WT2  = (float*)alloc((size_t)256 * 512 * 4);
    float* ball = (float*)alloc((size_t)3 * 512 * 4);
    int*   cnt   = (int*)alloc((size_t)N * 4);
    int*   offs  = (int*)alloc((size_t)(N + 1) * 4);
    int*   cur   = (int*)alloc((size_t)N * 4);
    int*   esrc  = (int*)alloc((size_t)E * 4);
    float* recip = (float*)alloc((size_t)N * 4);

    // zero-init state + histogram (covers pad rows too)
    hipMemsetAsync(hcbase, 0, 6 * fbytes, stream);
    hipMemsetAsync(cnt, 0, (size_t)N * 4, stream);

    bias_kernel<<<(3 * 512 + 255) / 256, 256, 0, stream>>>(bih, bhh, ball, 3 * 512);
    wt_kernel<<<(384 * 512 + 255) / 256, 256, 0, stream>>>(Wih0, 256, Whh, 256, 384, WT0);
    wt_kernel<<<(256 * 512 + 255) / 256, 256, 0, stream>>>(Wih_rest, 128, Whh + 512 * 128, 128, 256, WT1);
    wt_kernel<<<(256 * 512 + 255) / 256, 256, 0, stream>>>(Wih_rest + 512 * 128, 128, Whh + 2 * 512 * 128, 128, 256, WT2);
    feat0_kernel<<<(N * 128 + 255) / 256, 256, 0, stream>>>(features, W_in, b_in, feat0, N);
    hist_kernel<<<(E + 255) / 256, 256, 0, stream>>>(dst, cnt, E);
    scan_kernel<<<1, 1024, 0, stream>>>(cnt, offs, cur, recip, N);
    scatter_kernel<<<(E + 255) / 256, 256, 0, stream>>>(src, dst, cur, esrc, E);

    const int gx = (N + BM - 1) / BM;
    const int gagg = (N + 7) / 8;
    const float* featcur = feat0;
    for (int step = 0; step < 11; ++step) {
        agg_kernel<<<gagg, 256, 0, stream>>>(featcur, offs, esrc, recip, aggb, N);
        gemm_lstm<3><<<gx, 512, 0, stream>>>(aggb, featcur, h0, WT0, ball, c0, c0, h0, N);
        gemm_lstm<2><<<gx, 512, 0, stream>>>(h0, h1, nullptr, WT1, ball + 512, c1, c1, h1, N);
        gemm_lstm<2><<<gx, 512, 0, stream>>>(h1, h2, nullptr, WT2, ball + 1024, c2, c2, h2, N);
        featcur = h2;
    }
    out_kernel<<<N, 64, 0, stream>>>(h2, W_out, b_out, out);
}

// Round 3
// 1127.106 us; speedup vs baseline: 5.0557x; 4.0491x over previous
//
#include <hip/hip_runtime.h>
#include <math.h>

typedef _Float16 f16;
typedef __attribute__((ext_vector_type(8))) _Float16 half8;
typedef __attribute__((ext_vector_type(4))) float float4v;

// ---------------- helpers ----------------
__device__ __forceinline__ float fast_sigmoid(float x) { return 1.0f / (1.0f + __expf(-x)); }
__device__ __forceinline__ float fast_tanh(float x) {
    float a = fabsf(x);
    float e = __expf(-2.0f * a);
    float t = (1.0f - e) / (1.0f + e);
    return copysignf(t, x);
}

// async global->LDS, 16B per lane. LDS dest = wave-uniform base + lane*16.
__device__ __forceinline__ void async_copy16(const void* gsrc, void* ldst) {
    __builtin_amdgcn_global_load_lds(
        (const __attribute__((address_space(1))) void*)gsrc,
        (__attribute__((address_space(3))) void*)ldst,
        16, 0, 0);
}

// ---------------- prep kernels ----------------
// Build gate-permuted fp16 weights: Bp[col'][k], col' = dg*64 + q*16 + dl
// maps original gate-row j = q*128 + dg*16 + dl. k<Kih -> Wih[j][k], else Whh[j][k-Kih].
// Also bias bp[col'] = bih[j] + bhh[j].
__global__ void packb_kernel(const float* __restrict__ Wih, int Kih,
                             const float* __restrict__ Whh, int K,
                             const float* __restrict__ bih, const float* __restrict__ bhh,
                             f16* __restrict__ Bp, float* __restrict__ bp) {
    int t = blockIdx.x * blockDim.x + threadIdx.x;
    if (t >= (K << 9)) return;
    int colp = t / K;
    int k = t - colp * K;
    int dg = colp >> 6, q = (colp >> 4) & 3, dl = colp & 15;
    int j = q * 128 + dg * 16 + dl;
    float v = (k < Kih) ? Wih[j * Kih + k] : Whh[j * (K - Kih) + (k - Kih)];
    Bp[t] = (f16)v;
    if (k == 0) bp[colp] = bih[j] + bhh[j];
}

__global__ void feat0_kernel(const float* __restrict__ features, const float* __restrict__ W_in,
                             const float* __restrict__ b_in, f16* __restrict__ feat, int n) {
    int t = blockIdx.x * blockDim.x + threadIdx.x;
    if (t >= n * 128) return;
    int node = t >> 7;
    int d = t & 127;
    float s = b_in[d];
#pragma unroll
    for (int k = 0; k < 6; ++k) s += features[node * 6 + k] * W_in[k * 128 + d];
    feat[t] = (f16)fmaxf(s, 0.0f);
}

__global__ void hist_kernel(const int* __restrict__ dst, int* __restrict__ cnt, int e) {
    int t = blockIdx.x * blockDim.x + threadIdx.x;
    if (t < e) atomicAdd(&cnt[dst[t]], 1);
}

__global__ void scan_kernel(const int* __restrict__ cnt, int* __restrict__ off,
                            int* __restrict__ cur, float* __restrict__ recip, int n) {
    __shared__ int sums[1024];
    int t = threadIdx.x;
    int chunk = (n + 1023) >> 10;
    int s0 = t * chunk;
    int s1 = s0 + chunk; if (s1 > n) s1 = n;
    int s = 0;
    for (int i = s0; i < s1; ++i) s += cnt[i];
    sums[t] = s;
    __syncthreads();
    if (t == 0) {
        int acc = 0;
        for (int i = 0; i < 1024; ++i) { int v = sums[i]; sums[i] = acc; acc += v; }
        off[n] = acc;
    }
    __syncthreads();
    int acc = sums[t];
    for (int i = s0; i < s1; ++i) {
        off[i] = acc; cur[i] = acc;
        int c = cnt[i];
        recip[i] = (c > 0) ? 1.0f / (float)c : 0.0f;
        acc += c;
    }
}

__global__ void scatter_kernel(const int* __restrict__ src, const int* __restrict__ dst,
                               int* __restrict__ cur, int* __restrict__ esrc, int e) {
    int t = blockIdx.x * blockDim.x + threadIdx.x;
    if (t >= e) return;
    int d = dst[t];
    int p = atomicAdd(&cur[d], 1);
    esrc[p] = src[t];
}

// mean aggregation over fp16 feat: 16 lanes per node (8 halves = 16B each),
// 16 nodes per 256-thread block, fp32 accumulation, edge loop unrolled x4.
__global__ void agg_kernel(const f16* __restrict__ feat, const int* __restrict__ off,
                           const int* __restrict__ esrc, const float* __restrict__ recip,
                           f16* __restrict__ agg, int n) {
    int slot = threadIdx.x >> 4;   // 0..15
    int lane = threadIdx.x & 15;   // dim group: lane*8
    int v = blockIdx.x * 16 + slot;
    if (v >= n) return;
    int e0 = off[v], e1 = off[v + 1];
    float a[8];
#pragma unroll
    for (int j = 0; j < 8; ++j) a[j] = 0.0f;
    int e = e0;
    for (; e + 4 <= e1; e += 4) {
        int s0 = esrc[e], s1 = esrc[e + 1], s2 = esrc[e + 2], s3 = esrc[e + 3];
        half8 v0 = *(const half8*)&feat[(size_t)s0 * 128 + lane * 8];
        half8 v1 = *(const half8*)&feat[(size_t)s1 * 128 + lane * 8];
        half8 v2 = *(const half8*)&feat[(size_t)s2 * 128 + lane * 8];
        half8 v3 = *(const half8*)&feat[(size_t)s3 * 128 + lane * 8];
#pragma unroll
        for (int j = 0; j < 8; ++j)
            a[j] += (float)v0[j] + (float)v1[j] + (float)v2[j] + (float)v3[j];
    }
    for (; e < e1; ++e) {
        int s = esrc[e];
        half8 v0 = *(const half8*)&feat[(size_t)s * 128 + lane * 8];
#pragma unroll
        for (int j = 0; j < 8; ++j) a[j] += (float)v0[j];
    }
    float r = recip[v];
    half8 o;
#pragma unroll
    for (int j = 0; j < 8; ++j) o[j] = (f16)(a[j] * r);
    *(half8*)&agg[(size_t)v * 128 + lane * 8] = o;
}

// ---------------- fused MFMA GEMM + LSTM cell ----------------
// gates[n][col'] = sum_k A[n][k] * Bp[col'][k] + bp[col']  (fp32 accum via MFMA)
// col' = dg*64 + q*16 + dl encodes (gate q, dim d = dg*16+dl) so each wave's
// 64-col tile holds all 4 gates for 16 dims -> lane-local LSTM epilogue.
// Block: 256 threads = 4 waves, tile BM=64 x 256 cols (blockIdx.y = col half).
// Wave w: 64 rows x 64 cols = 4x4 grid of 16x16x32 f16 MFMA.
#define BM 64

template <int PARTS>
__global__ __launch_bounds__(256, 3) void gemm_lstm(
    const f16* __restrict__ A0, const f16* __restrict__ A1, const f16* __restrict__ A2,
    const f16* __restrict__ Bp, const float* __restrict__ bp,
    const float* __restrict__ c_in, float* __restrict__ c_out, f16* __restrict__ h_out,
    int nrows) {
    constexpr int K = PARTS * 128;
    __shared__ f16 As[64 * 32];    // [row][k] 4 KB
    __shared__ f16 Bs[256 * 32];   // [col'][k] 16 KB

    const int tid = threadIdx.x;
    const int w = tid >> 6;      // wave 0..3
    const int lane = tid & 63;
    const int dl = lane & 15;
    const int quad = lane >> 4;
    const int row0 = blockIdx.x * BM;
    const int cb = blockIdx.y;   // 0..1

    float4v acc[4][4];  // [row-tile rt][gate q]
#pragma unroll
    for (int q = 0; q < 4; ++q) {
        float b = bp[cb * 256 + w * 64 + q * 16 + dl];
#pragma unroll
        for (int rt = 0; rt < 4; ++rt) {
            acc[rt][q][0] = b; acc[rt][q][1] = b; acc[rt][q][2] = b; acc[rt][q][3] = b;
        }
    }

    const int srow = lane >> 2;       // staging row within 16-row group
    const int soff = (lane & 3) * 8;  // staging k-offset (halves)

    for (int kt = 0; kt < PARTS * 4; ++kt) {
        const f16* Ap = A0;
        const int pi = kt >> 2;
        if (PARTS >= 2 && pi == 1) Ap = A1;
        if (PARTS >= 3 && pi == 2) Ap = A2;
        const int kk = (kt & 3) * 32;

        __syncthreads();  // previous iteration's ds_reads complete
        // stage A: wave w covers rows w*16..+15
        async_copy16(&Ap[(size_t)(row0 + w * 16 + srow) * 128 + kk + soff],
                     (f16*)As + w * 512);
        // stage B: 4 calls/wave, chunk m = i*4+w covers rows m*16..+15 of the 256-col half
        const f16* Bbase = Bp + (size_t)(cb * 256) * K + kt * 32;
#pragma unroll
        for (int i = 0; i < 4; ++i) {
            int m = i * 4 + w;
            async_copy16(&Bbase[(size_t)(m * 16 + srow) * K + soff], (f16*)Bs + m * 512);
        }
        __syncthreads();  // vmcnt(0) drain: staging visible

        half8 a[4], b[4];
#pragma unroll
        for (int rt = 0; rt < 4; ++rt)
            a[rt] = *(const half8*)&As[(rt * 16 + dl) * 32 + quad * 8];
#pragma unroll
        for (int q = 0; q < 4; ++q)
            b[q] = *(const half8*)&Bs[((w * 4 + q) * 16 + dl) * 32 + quad * 8];
#pragma unroll
        for (int rt = 0; rt < 4; ++rt)
#pragma unroll
            for (int q = 0; q < 4; ++q)
                acc[rt][q] = __builtin_amdgcn_mfma_f32_16x16x32_f16(a[rt], b[q], acc[rt][q], 0, 0, 0);
    }

    // epilogue: lane owns dim d, rows rt*16 + quad*4 + r, all 4 gates in acc[rt][*]
    const int d = cb * 64 + w * 16 + dl;
#pragma unroll
    for (int rt = 0; rt < 4; ++rt) {
#pragma unroll
        for (int r = 0; r < 4; ++r) {
            int n = row0 + rt * 16 + quad * 4 + r;
            if (n < nrows) {
                float ig = fast_sigmoid(acc[rt][0][r]);
                float fg = fast_sigmoid(acc[rt][1][r]);
                float gg = fast_tanh(acc[rt][2][r]);
                float og = fast_sigmoid(acc[rt][3][r]);
                float cold = c_in[(size_t)n * 128 + d];
                float cn = fg * cold + ig * gg;
                c_out[(size_t)n * 128 + d] = cn;
                h_out[(size_t)n * 128 + d] = (f16)(og * fast_tanh(cn));
            }
        }
    }
}

// ---------------- output projection ----------------
__global__ void out_kernel(const f16* __restrict__ h2, const float* __restrict__ Wout,
                           const float* __restrict__ bout, float* __restrict__ out) {
    int n = blockIdx.x;
    int l = threadIdx.x;  // 0..63
    float v = (float)h2[(size_t)n * 128 + l] * Wout[l] +
              (float)h2[(size_t)n * 128 + 64 + l] * Wout[64 + l];
#pragma unroll
    for (int o = 32; o > 0; o >>= 1) v += __shfl_down(v, o, 64);
    if (l == 0) out[n] = v + bout[0];
}

// ---------------- launch ----------------
extern "C" void kernel_launch(void* const* d_in, const int* in_sizes, int n_in,
                              void* d_out, int out_size, void* d_ws, size_t ws_size,
                              hipStream_t stream) {
    const float* features = (const float*)d_in[0];
    const int*   src      = (const int*)d_in[1];
    const int*   dst      = (const int*)d_in[2];
    const float* W_in     = (const float*)d_in[3];
    const float* b_in     = (const float*)d_in[4];
    const float* Wih0     = (const float*)d_in[5];
    const float* Wih_rest = (const float*)d_in[6];
    const float* Whh      = (const float*)d_in[7];
    const float* bih      = (const float*)d_in[8];
    const float* bhh      = (const float*)d_in[9];
    const float* W_out    = (const float*)d_in[10];
    const float* b_out    = (const float*)d_in[11];
    float* out = (float*)d_out;

    const int N = in_sizes[0] / 6;  // 20000
    const int E = in_sizes[1];      // 640000
    const int NP = N + BM;          // padded rows: staging never reads unmapped mem

    char* ws = (char*)d_ws;
    size_t pos = 0;
    auto alloc = [&](size_t bytes) -> void* {
        void* p = ws + pos;
        pos = (pos + bytes + 255) & ~(size_t)255;
        return p;
    };
    const size_t hrow = 128;
    const size_t hbytes = (size_t)NP * hrow * sizeof(f16);   // fp16 activation matrix
    const size_t cbytes = (size_t)NP * hrow * sizeof(float); // fp32 cell state
    f16* feath = (f16*)alloc(hbytes);
    f16* aggh  = (f16*)alloc(hbytes);
    f16* hblk  = (f16*)alloc(3 * hbytes);
    f16* h0 = hblk + 0 * (size_t)NP * hrow;
    f16* h1 = hblk + 1 * (size_t)NP * hrow;
    f16* h2 = hblk + 2 * (size_t)NP * hrow;
    float* cblk = (float*)alloc(3 * cbytes);
    float* c0 = cblk + 0 * (size_t)NP * hrow;
    float* c1 = cblk + 1 * (size_t)NP * hrow;
    float* c2 = cblk + 2 * (size_t)NP * hrow;
    f16* Bp0 = (f16*)alloc((size_t)512 * 384 * sizeof(f16));
    f16* Bp1 = (f16*)alloc((size_t)512 * 256 * sizeof(f16));
    f16* Bp2 = (f16*)alloc((size_t)512 * 256 * sizeof(f16));
    float* bp0 = (float*)alloc(512 * sizeof(float));
    float* bp1 = (float*)alloc(512 * sizeof(float));
    float* bp2 = (float*)alloc(512 * sizeof(float));
    int*   cnt   = (int*)alloc((size_t)N * 4);
    int*   offs  = (int*)alloc((size_t)(N + 1) * 4);
    int*   cur   = (int*)alloc((size_t)N * 4);
    int*   esrc  = (int*)alloc((size_t)E * 4);
    float* recip = (float*)alloc((size_t)N * 4);

    hipMemsetAsync(hblk, 0, 3 * hbytes, stream);
    hipMemsetAsync(cblk, 0, 3 * cbytes, stream);
    hipMemsetAsync(cnt, 0, (size_t)N * 4, stream);

    // weight packing (once per launch)
    packb_kernel<<<(512 * 384 + 255) / 256, 256, 0, stream>>>(
        Wih0, 256, Whh, 384, bih, bhh, Bp0, bp0);
    packb_kernel<<<(512 * 256 + 255) / 256, 256, 0, stream>>>(
        Wih_rest, 128, Whh + 512 * 128, 256, bih + 512, bhh + 512, Bp1, bp1);
    packb_kernel<<<(512 * 256 + 255) / 256, 256, 0, stream>>>(
        Wih_rest + 512 * 128, 128, Whh + 2 * 512 * 128, 256, bih + 1024, bhh + 1024, Bp2, bp2);

    feat0_kernel<<<(N * 128 + 255) / 256, 256, 0, stream>>>(features, W_in, b_in, feath, N);
    hist_kernel<<<(E + 255) / 256, 256, 0, stream>>>(dst, cnt, E);
    scan_kernel<<<1, 1024, 0, stream>>>(cnt, offs, cur, recip, N);
    scatter_kernel<<<(E + 255) / 256, 256, 0, stream>>>(src, dst, cur, esrc, E);

    const dim3 ggrid((N + BM - 1) / BM, 2, 1);
    const int gagg = (N + 15) / 16;
    const f16* featcur = feath;
    for (int step = 0; step < 11; ++step) {
        agg_kernel<<<gagg, 256, 0, stream>>>(featcur, offs, esrc, recip, aggh, N);
        gemm_lstm<3><<<ggrid, 256, 0, stream>>>(aggh, featcur, h0, Bp0, bp0, c0, c0, h0, N);
        gemm_lstm<2><<<ggrid, 256, 0, stream>>>(h0, h1, nullptr, Bp1, bp1, c1, c1, h1, N);
        gemm_lstm<2><<<ggrid, 256, 0, stream>>>(h1, h2, nullptr, Bp2, bp2, c2, c2, h2, N);
        featcur = h2;
    }
    out_kernel<<<N, 64, 0, stream>>>(h2, W_out, b_out, out);
}